// Round 1
// baseline (642.866 us; speedup 1.0000x reference)
//
#include <hip/hip_runtime.h>
#include <hip/hip_bf16.h>

#define BB 32
#define SS 4096
#define HH 512
#define EE 512
#define NEGV -1000000000.0f

using float4v = __attribute__((ext_vector_type(4))) float;
using short8v = __attribute__((ext_vector_type(8))) short;
using short4v = __attribute__((ext_vector_type(4))) short;

__device__ inline unsigned short f2bf(float x) {
    union { float f; unsigned int u; } c; c.f = x;
    unsigned int r = c.u + 0x7FFFu + ((c.u >> 16) & 1u);  // RNE
    return (unsigned short)(r >> 16);
}

// qp[b][h] = sum_e query[b][e]*Wq[e][h] + bq[h] + bk[h]   (bk folded in)
__global__ void qproj_kernel(const float* __restrict__ query, const float* __restrict__ Wq,
                             const float* __restrict__ bq, const float* __restrict__ bk,
                             float* __restrict__ qp) {
    __shared__ float qs[HH];
    int b = blockIdx.x, t = threadIdx.x;  // 256 threads
    for (int i = t; i < HH; i += 256) qs[i] = query[b * HH + i];
    __syncthreads();
    int h0 = t, h1 = t + 256;
    float a0 = 0.f, a1 = 0.f;
    for (int e = 0; e < EE; ++e) {
        float q = qs[e];
        a0 += q * Wq[e * HH + h0];
        a1 += q * Wq[e * HH + h1];
    }
    qp[b * HH + h0] = a0 + bq[h0] + bk[h0];
    qp[b * HH + h1] = a1 + bq[h1] + bk[h1];
}

// WkT[h][e] = bf16(Wk[e][h])  -- so scores kernel's B-fragments are contiguous
__global__ void wkt_kernel(const float* __restrict__ Wk, unsigned short* __restrict__ WkT) {
    __shared__ float tile[32][33];
    int e0 = blockIdx.x * 32, h0 = blockIdx.y * 32;
    int tx = threadIdx.x, ty = threadIdx.y;  // (32,8)
    #pragma unroll
    for (int i = 0; i < 4; ++i)
        tile[ty + 8 * i][tx] = Wk[(size_t)(e0 + ty + 8 * i) * HH + h0 + tx];
    __syncthreads();
    #pragma unroll
    for (int i = 0; i < 4; ++i)
        WkT[(size_t)(h0 + ty + 8 * i) * EE + e0 + tx] = f2bf(tile[tx][ty + 8 * i]);
}

// Per block: b = blockIdx.y, s-tile of 64 rows. Computes
// scores[b][s] = bv + sum_h v[h]*tanh(qp[b][h] + (keys_tile @ Wk)[s][h]), masked.
__launch_bounds__(256, 2)
__global__ void scores_kernel(const float* __restrict__ keys, const unsigned short* __restrict__ WkT,
                              const float* __restrict__ qp, const float* __restrict__ v,
                              const float* __restrict__ bv, const int* __restrict__ mask,
                              float* __restrict__ scores) {
    constexpr int LDK = EE + 8;  // pad: row stride 1040 B -> A-frag ds_read_b128 2-way max
    __shared__ unsigned short klds[64 * LDK];
    __shared__ float qp_lds[HH];
    __shared__ float v_lds[HH];
    __shared__ float red[4][64];
    int b = blockIdx.y, s0 = blockIdx.x * 64;
    int tid = threadIdx.x;

    for (int i = tid; i < HH; i += 256) { qp_lds[i] = qp[b * HH + i]; v_lds[i] = v[i]; }

    // stage 64x512 keys tile fp32 -> bf16 LDS (coalesced float4 loads)
    const float4v* ksrc = (const float4v*)(keys + ((size_t)b * SS + s0) * EE);
    for (int i = tid; i < 64 * 128; i += 256) {
        int row = i >> 7, c4 = i & 127;
        float4v kv = ksrc[row * 128 + c4];
        short4v p;
        p.x = (short)f2bf(kv.x); p.y = (short)f2bf(kv.y);
        p.z = (short)f2bf(kv.z); p.w = (short)f2bf(kv.w);
        *(short4v*)(&klds[row * LDK + c4 * 4]) = p;
    }
    __syncthreads();

    int w = tid >> 6, lane = tid & 63;
    int lq = lane >> 4, lr = lane & 15;

    float part[4][4];
    #pragma unroll
    for (int m = 0; m < 4; ++m)
        #pragma unroll
        for (int r = 0; r < 4; ++r) part[m][r] = 0.f;

    // wave w owns n-tiles [w*8, w*8+8): each B-frag loaded once per block.
    #pragma unroll
    for (int ng = 0; ng < 2; ++ng) {
        int nt0 = w * 8 + ng * 4;
        float4v acc[4][4];  // [m_tile][n_sub]
        #pragma unroll
        for (int m = 0; m < 4; ++m)
            #pragma unroll
            for (int j = 0; j < 4; ++j) acc[m][j] = (float4v){0.f, 0.f, 0.f, 0.f};

        for (int k0 = 0; k0 < EE; k0 += 32) {
            short8v bfrag[4];
            #pragma unroll
            for (int j = 0; j < 4; ++j) {
                int nrow = (nt0 + j) * 16 + lr;  // h index
                bfrag[j] = *(const short8v*)(WkT + (size_t)nrow * EE + k0 + lq * 8);
            }
            #pragma unroll
            for (int m = 0; m < 4; ++m) {
                short8v afrag = *(const short8v*)(&klds[(m * 16 + lr) * LDK + k0 + lq * 8]);
                #pragma unroll
                for (int j = 0; j < 4; ++j)
                    acc[m][j] = __builtin_amdgcn_mfma_f32_16x16x32_bf16(afrag, bfrag[j], acc[m][j], 0, 0, 0);
            }
        }
        // fused epilogue: score_partial += v[h] * tanh(qp[h] + kp)
        #pragma unroll
        for (int j = 0; j < 4; ++j) {
            int h = (nt0 + j) * 16 + lr;
            float vj = v_lds[h], qj = qp_lds[h];
            #pragma unroll
            for (int m = 0; m < 4; ++m) {
                #pragma unroll
                for (int r = 0; r < 4; ++r) {
                    float x = qj + acc[m][j][r];
                    x = fminf(fmaxf(x, -12.f), 12.f);
                    float e2 = __expf(2.f * x);
                    part[m][r] += vj * ((e2 - 1.f) / (e2 + 1.f));
                }
            }
        }
    }

    // sum across the 16 lanes of each quad-group (same s-row)
    #pragma unroll
    for (int m = 0; m < 4; ++m)
        #pragma unroll
        for (int r = 0; r < 4; ++r) {
            float p = part[m][r];
            p += __shfl_xor(p, 1, 16);
            p += __shfl_xor(p, 2, 16);
            p += __shfl_xor(p, 4, 16);
            p += __shfl_xor(p, 8, 16);
            part[m][r] = p;
        }
    if (lr == 0) {
        #pragma unroll
        for (int m = 0; m < 4; ++m)
            #pragma unroll
            for (int r = 0; r < 4; ++r)
                red[w][m * 16 + lq * 4 + r] = part[m][r];
    }
    __syncthreads();
    if (tid < 64) {
        float sc = red[0][tid] + red[1][tid] + red[2][tid] + red[3][tid] + bv[0];
        int s = s0 + tid;
        if (mask[b * SS + s] == 0) sc = NEGV;
        scores[b * SS + s] = sc;
    }
}

__global__ void softmax_kernel(const float* __restrict__ scores, float* __restrict__ attn) {
    __shared__ float red[1024];
    int b = blockIdx.x, t = threadIdx.x;  // 1024 threads
    float s_[4], e_[4];
    float lmax = -3e38f;
    #pragma unroll
    for (int i = 0; i < 4; ++i) { s_[i] = scores[b * SS + t + i * 1024]; lmax = fmaxf(lmax, s_[i]); }
    red[t] = lmax; __syncthreads();
    for (int off = 512; off > 0; off >>= 1) {
        if (t < off) red[t] = fmaxf(red[t], red[t + off]);
        __syncthreads();
    }
    float mx = red[0]; __syncthreads();
    float lsum = 0.f;
    #pragma unroll
    for (int i = 0; i < 4; ++i) { e_[i] = __expf(s_[i] - mx); lsum += e_[i]; }
    red[t] = lsum; __syncthreads();
    for (int off = 512; off > 0; off >>= 1) {
        if (t < off) red[t] += red[t + off];
        __syncthreads();
    }
    float inv = 1.f / red[0];
    #pragma unroll
    for (int i = 0; i < 4; ++i) attn[b * SS + t + i * 1024] = e_[i] * inv;
}

// context[b][e] = sum_s attn[b][s]*keys[b][s][e]; grid (S/128, B), partial sums via atomicAdd
__global__ void context_kernel(const float* __restrict__ keys, const float* __restrict__ attn,
                               float* __restrict__ ctx) {
    __shared__ float a_s[128];
    int chunk = blockIdx.x, b = blockIdx.y, t = threadIdx.x;  // 256 threads
    if (t < 128) a_s[t] = attn[b * SS + chunk * 128 + t];
    __syncthreads();
    const float* kbase = keys + ((size_t)b * SS + (size_t)chunk * 128) * EE;
    int e0 = t * 2;
    float ax = 0.f, ay = 0.f;
    for (int ss = 0; ss < 128; ++ss) {
        float2 kv = *(const float2*)(kbase + (size_t)ss * EE + e0);
        float a = a_s[ss];
        ax += a * kv.x; ay += a * kv.y;
    }
    atomicAdd(&ctx[b * EE + e0], ax);
    atomicAdd(&ctx[b * EE + e0 + 1], ay);
}

extern "C" void kernel_launch(void* const* d_in, const int* in_sizes, int n_in,
                              void* d_out, int out_size, void* d_ws, size_t ws_size,
                              hipStream_t stream) {
    const float* query = (const float*)d_in[0];
    const float* keys  = (const float*)d_in[1];
    const int*   mask  = (const int*)d_in[2];
    const float* Wq    = (const float*)d_in[3];
    const float* bq    = (const float*)d_in[4];
    const float* Wk    = (const float*)d_in[5];
    const float* bk    = (const float*)d_in[6];
    const float* v     = (const float*)d_in[7];
    const float* bv    = (const float*)d_in[8];

    float* out  = (float*)d_out;
    float* ctx  = out;            // (B, E)
    float* attn = out + BB * EE;  // (B, S)

    char* ws = (char*)d_ws;
    float* qp = (float*)ws;                                        // 65536 B
    unsigned short* WkT = (unsigned short*)(ws + 65536);           // 524288 B
    float* scores = (float*)(ws + 65536 + 524288);                 // 524288 B

    hipMemsetAsync(ctx, 0, BB * EE * sizeof(float), stream);
    qproj_kernel<<<BB, 256, 0, stream>>>(query, Wq, bq, bk, qp);
    wkt_kernel<<<dim3(EE / 32, HH / 32), dim3(32, 8), 0, stream>>>(Wk, WkT);
    scores_kernel<<<dim3(SS / 64, BB), 256, 0, stream>>>(keys, WkT, qp, v, bv, mask, scores);
    softmax_kernel<<<BB, 1024, 0, stream>>>(scores, attn);
    context_kernel<<<dim3(SS / 128, BB), 256, 0, stream>>>(keys, attn, ctx);
}

// Round 2
// 585.308 us; speedup vs baseline: 1.0983x; 1.0983x over previous
//
#include <hip/hip_runtime.h>
#include <hip/hip_bf16.h>

#define BB 32
#define SS 4096
#define HH 512
#define EE 512
#define NEGV -1000000000.0f

using float4v = __attribute__((ext_vector_type(4))) float;
using short8v = __attribute__((ext_vector_type(8))) short;
using short4v = __attribute__((ext_vector_type(4))) short;

__device__ inline unsigned short f2bf(float x) {
    union { float f; unsigned int u; } c; c.f = x;
    unsigned int r = c.u + 0x7FFFu + ((c.u >> 16) & 1u);  // RNE
    return (unsigned short)(r >> 16);
}

// Partial q-projection: grid (4, B); block handles e-range of 128, atomicAdd into qp.
// Biases (bq+bk) are folded in at the scores kernel's qp read.
__global__ void qproj_kernel(const float* __restrict__ query, const float* __restrict__ Wq,
                             float* __restrict__ qp) {
    __shared__ float qs[128];
    int b = blockIdx.y, e0 = blockIdx.x * 128, t = threadIdx.x;  // 256 threads
    if (t < 128) qs[t] = query[b * HH + e0 + t];
    __syncthreads();
    int h0 = t, h1 = t + 256;
    float a0 = 0.f, a1 = 0.f;
    for (int e = 0; e < 128; ++e) {
        float q = qs[e];
        a0 += q * Wq[(size_t)(e0 + e) * HH + h0];
        a1 += q * Wq[(size_t)(e0 + e) * HH + h1];
    }
    atomicAdd(&qp[b * HH + h0], a0);
    atomicAdd(&qp[b * HH + h1], a1);
}

// Repack Wk (E,H) fp32 -> fragment-linear bf16 tiles:
// frag[ks][nt][lane] = 16B holding Wk[e = ks*32 + lq*8 + j][h = nt*16 + lr], j=0..7
// where lq = lane>>4, lr = lane&15. A wave's B-frag load is then one contiguous 1KB burst.
__global__ void wkt_kernel(const float* __restrict__ Wk, unsigned short* __restrict__ WkT) {
    int g = blockIdx.x * 256 + threadIdx.x;  // 0 .. 16*32*64-1 = 32767
    int lane = g & 63, nt = (g >> 6) & 31, ks = g >> 11;
    int lq = lane >> 4, lr = lane & 15;
    int h = nt * 16 + lr;
    int e0 = ks * 32 + lq * 8;
    short8v o;
    #pragma unroll
    for (int j = 0; j < 8; ++j) o[j] = (short)f2bf(Wk[(size_t)(e0 + j) * HH + h]);
    *(short8v*)(WkT + (size_t)g * 8) = o;
}

// Per block: b = blockIdx.y, s-tile of 64 rows. Computes
// scores[b][s] = bv + sum_h v[h]*tanh(qp[b][h]+bq[h]+bk[h] + (keys_tile @ Wk)[s][h]), masked.
__launch_bounds__(256, 2)
__global__ void scores_kernel(const float* __restrict__ keys, const unsigned short* __restrict__ WkT,
                              const float* __restrict__ qp, const float* __restrict__ bq,
                              const float* __restrict__ bk, const float* __restrict__ v,
                              const float* __restrict__ bv, const int* __restrict__ mask,
                              float* __restrict__ scores) {
    constexpr int LDK = EE + 8;  // pad keeps A-frag ds_read_b128 spread over all 32 banks
    __shared__ unsigned short klds[64 * LDK];
    __shared__ float qp_lds[HH];
    __shared__ float v_lds[HH];
    __shared__ float red[4][64];
    int b = blockIdx.y, s0 = blockIdx.x * 64;
    int tid = threadIdx.x;

    for (int i = tid; i < HH; i += 256) {
        qp_lds[i] = qp[b * HH + i] + bq[i] + bk[i];
        v_lds[i] = v[i];
    }

    // stage 64x512 keys tile fp32 -> bf16 LDS (coalesced float4 loads)
    const float4v* ksrc = (const float4v*)(keys + ((size_t)b * SS + s0) * EE);
    for (int i = tid; i < 64 * 128; i += 256) {
        int row = i >> 7, c4 = i & 127;
        float4v kv = ksrc[row * 128 + c4];
        short4v p;
        p.x = (short)f2bf(kv.x); p.y = (short)f2bf(kv.y);
        p.z = (short)f2bf(kv.z); p.w = (short)f2bf(kv.w);
        *(short4v*)(&klds[row * LDK + c4 * 4]) = p;
    }
    __syncthreads();

    int w = tid >> 6, lane = tid & 63;
    int lq = lane >> 4, lr = lane & 15;

    float part[4][4];
    #pragma unroll
    for (int m = 0; m < 4; ++m)
        #pragma unroll
        for (int r = 0; r < 4; ++r) part[m][r] = 0.f;

    const short8v* Wf = (const short8v*)WkT;  // frag units: (ks*32 + nt)*64 + lane

    // wave w owns n-tiles [w*8, w*8+8); B-frags are coalesced 1KB bursts from L2.
    #pragma unroll
    for (int ng = 0; ng < 2; ++ng) {
        int nt0 = w * 8 + ng * 4;
        const short8v* Wb = Wf + (size_t)nt0 * 64 + lane;
        float4v acc[4][4];  // [m_tile][n_sub]
        #pragma unroll
        for (int m = 0; m < 4; ++m)
            #pragma unroll
            for (int j = 0; j < 4; ++j) acc[m][j] = (float4v){0.f, 0.f, 0.f, 0.f};

        short8v bcur[4];
        #pragma unroll
        for (int j = 0; j < 4; ++j) bcur[j] = Wb[j * 64];

        for (int ks = 0; ks < 16; ++ks) {
            short8v bnxt[4];
            if (ks < 15) {
                #pragma unroll
                for (int j = 0; j < 4; ++j) bnxt[j] = Wb[(size_t)(ks + 1) * 2048 + j * 64];
            }
            #pragma unroll
            for (int m = 0; m < 4; ++m) {
                short8v afrag = *(const short8v*)(&klds[(m * 16 + lr) * LDK + ks * 32 + lq * 8]);
                #pragma unroll
                for (int j = 0; j < 4; ++j)
                    acc[m][j] = __builtin_amdgcn_mfma_f32_16x16x32_bf16(afrag, bcur[j], acc[m][j], 0, 0, 0);
            }
            if (ks < 15) {
                #pragma unroll
                for (int j = 0; j < 4; ++j) bcur[j] = bnxt[j];
            }
        }
        // fused epilogue: score_partial += v[h] * tanh(qp[h] + kp)
        #pragma unroll
        for (int j = 0; j < 4; ++j) {
            int h = (nt0 + j) * 16 + lr;
            float vj = v_lds[h], qj = qp_lds[h];
            #pragma unroll
            for (int m = 0; m < 4; ++m) {
                #pragma unroll
                for (int r = 0; r < 4; ++r) {
                    float x = qj + acc[m][j][r];
                    x = fminf(fmaxf(x, -12.f), 12.f);
                    float e2 = __expf(2.f * x);
                    part[m][r] += vj * ((e2 - 1.f) / (e2 + 1.f));
                }
            }
        }
    }

    // sum across the 16 lanes of each quad-group (same s-row)
    #pragma unroll
    for (int m = 0; m < 4; ++m)
        #pragma unroll
        for (int r = 0; r < 4; ++r) {
            float p = part[m][r];
            p += __shfl_xor(p, 1, 16);
            p += __shfl_xor(p, 2, 16);
            p += __shfl_xor(p, 4, 16);
            p += __shfl_xor(p, 8, 16);
            part[m][r] = p;
        }
    if (lr == 0) {
        #pragma unroll
        for (int m = 0; m < 4; ++m)
            #pragma unroll
            for (int r = 0; r < 4; ++r)
                red[w][m * 16 + lq * 4 + r] = part[m][r];
    }
    __syncthreads();
    if (tid < 64) {
        float sc = red[0][tid] + red[1][tid] + red[2][tid] + red[3][tid] + bv[0];
        int s = s0 + tid;
        if (mask[b * SS + s] == 0) sc = NEGV;
        scores[b * SS + s] = sc;
    }
}

__global__ void softmax_kernel(const float* __restrict__ scores, float* __restrict__ attn) {
    __shared__ float red[1024];
    int b = blockIdx.x, t = threadIdx.x;  // 1024 threads
    float s_[4], e_[4];
    float lmax = -3e38f;
    #pragma unroll
    for (int i = 0; i < 4; ++i) { s_[i] = scores[b * SS + t + i * 1024]; lmax = fmaxf(lmax, s_[i]); }
    red[t] = lmax; __syncthreads();
    for (int off = 512; off > 0; off >>= 1) {
        if (t < off) red[t] = fmaxf(red[t], red[t + off]);
        __syncthreads();
    }
    float mx = red[0]; __syncthreads();
    float lsum = 0.f;
    #pragma unroll
    for (int i = 0; i < 4; ++i) { e_[i] = __expf(s_[i] - mx); lsum += e_[i]; }
    red[t] = lsum; __syncthreads();
    for (int off = 512; off > 0; off >>= 1) {
        if (t < off) red[t] += red[t + off];
        __syncthreads();
    }
    float inv = 1.f / red[0];
    #pragma unroll
    for (int i = 0; i < 4; ++i) attn[b * SS + t + i * 1024] = e_[i] * inv;
}

// context[b][e] = sum_s attn[b][s]*keys[b][s][e]; grid (S/128, B), float4 loads,
// partial sums via atomicAdd
__global__ void context_kernel(const float* __restrict__ keys, const float* __restrict__ attn,
                               float* __restrict__ ctx) {
    __shared__ float a_s[128];
    int chunk = blockIdx.x, b = blockIdx.y, t = threadIdx.x;  // 256 threads
    if (t < 128) a_s[t] = attn[b * SS + chunk * 128 + t];
    __syncthreads();
    const float* kbase = keys + ((size_t)b * SS + (size_t)chunk * 128) * EE;
    int e0 = (t & 127) * 4, sr = t >> 7;
    float4v acc = (float4v){0.f, 0.f, 0.f, 0.f};
    for (int ss = sr; ss < 128; ss += 2) {
        float4v kv = *(const float4v*)(kbase + (size_t)ss * EE + e0);
        float a = a_s[ss];
        acc.x += a * kv.x; acc.y += a * kv.y; acc.z += a * kv.z; acc.w += a * kv.w;
    }
    atomicAdd(&ctx[b * EE + e0 + 0], acc.x);
    atomicAdd(&ctx[b * EE + e0 + 1], acc.y);
    atomicAdd(&ctx[b * EE + e0 + 2], acc.z);
    atomicAdd(&ctx[b * EE + e0 + 3], acc.w);
}

extern "C" void kernel_launch(void* const* d_in, const int* in_sizes, int n_in,
                              void* d_out, int out_size, void* d_ws, size_t ws_size,
                              hipStream_t stream) {
    const float* query = (const float*)d_in[0];
    const float* keys  = (const float*)d_in[1];
    const int*   mask  = (const int*)d_in[2];
    const float* Wq    = (const float*)d_in[3];
    const float* bq    = (const float*)d_in[4];
    const float* Wk    = (const float*)d_in[5];
    const float* bk    = (const float*)d_in[6];
    const float* v     = (const float*)d_in[7];
    const float* bv    = (const float*)d_in[8];

    float* out  = (float*)d_out;
    float* ctx  = out;            // (B, E)
    float* attn = out + BB * EE;  // (B, S)

    char* ws = (char*)d_ws;
    float* qp = (float*)ws;                                        // 65536 B
    unsigned short* WkT = (unsigned short*)(ws + 65536);           // 524288 B (fragment-linear)
    float* scores = (float*)(ws + 65536 + 524288);                 // 524288 B

    hipMemsetAsync(ctx, 0, BB * EE * sizeof(float), stream);
    hipMemsetAsync(qp, 0, BB * HH * sizeof(float), stream);
    qproj_kernel<<<dim3(4, BB), 256, 0, stream>>>(query, Wq, qp);
    wkt_kernel<<<128, 256, 0, stream>>>(Wk, WkT);
    scores_kernel<<<dim3(SS / 64, BB), 256, 0, stream>>>(keys, WkT, qp, bq, bk, v, bv, mask, scores);
    softmax_kernel<<<BB, 1024, 0, stream>>>(scores, attn);
    context_kernel<<<dim3(SS / 128, BB), 256, 0, stream>>>(keys, attn, ctx);
}

// Round 3
// 509.223 us; speedup vs baseline: 1.2624x; 1.1494x over previous
//
#include <hip/hip_runtime.h>
#include <hip/hip_bf16.h>

#define BB 32
#define SS 4096
#define HH 512
#define EE 512
#define NEGV -1000000000.0f

using float4v = __attribute__((ext_vector_type(4))) float;
using short8v = __attribute__((ext_vector_type(8))) short;
using short4v = __attribute__((ext_vector_type(4))) short;

__device__ inline unsigned short f2bf(float x) {
    union { float f; unsigned int u; } c; c.f = x;
    unsigned int r = c.u + 0x7FFFu + ((c.u >> 16) & 1u);  // RNE
    return (unsigned short)(r >> 16);
}

// Partial q-projection: grid (4, B); block handles e-range of 128, atomicAdd into qp.
// Biases (bq+bk) are folded in at the scores kernel's qp read.
__global__ void qproj_kernel(const float* __restrict__ query, const float* __restrict__ Wq,
                             float* __restrict__ qp) {
    __shared__ float qs[128];
    int b = blockIdx.y, e0 = blockIdx.x * 128, t = threadIdx.x;  // 256 threads
    if (t < 128) qs[t] = query[b * HH + e0 + t];
    __syncthreads();
    int h0 = t, h1 = t + 256;
    float a0 = 0.f, a1 = 0.f;
    for (int e = 0; e < 128; ++e) {
        float q = qs[e];
        a0 += q * Wq[(size_t)(e0 + e) * HH + h0];
        a1 += q * Wq[(size_t)(e0 + e) * HH + h1];
    }
    atomicAdd(&qp[b * HH + h0], a0);
    atomicAdd(&qp[b * HH + h1], a1);
}

// Repack Wk (E,H) fp32 -> fragment-linear bf16 tiles:
// frag[ks][nt][lane] = 16B holding Wk[e = ks*32 + lq*8 + j][h = nt*16 + lr], j=0..7
// (lq = lane>>4, lr = lane&15). A wave's B-frag load is one contiguous 1KB burst.
__global__ void wkt_kernel(const float* __restrict__ Wk, unsigned short* __restrict__ WkT) {
    int g = blockIdx.x * 256 + threadIdx.x;  // 0 .. 16*32*64-1
    int lane = g & 63, nt = (g >> 6) & 31, ks = g >> 11;
    int lq = lane >> 4, lr = lane & 15;
    int h = nt * 16 + lr;
    int e0 = ks * 32 + lq * 8;
    short8v o;
    #pragma unroll
    for (int j = 0; j < 8; ++j) o[j] = (short)f2bf(Wk[(size_t)(e0 + j) * HH + h]);
    *(short8v*)(WkT + (size_t)g * 8) = o;
}

// Per block: b = blockIdx.y, s-tile of 64 rows, 512 threads (8 waves).
// Wave w owns n-tiles [w*4, w*4+4); K staged to LDS in two 256-wide chunks so
// LDS stays ~40KB -> 2 blocks/CU -> 4 waves/SIMD for latency hiding.
__launch_bounds__(512, 4)
__global__ void scores_kernel(const float* __restrict__ keys, const unsigned short* __restrict__ WkT,
                              const float* __restrict__ qp, const float* __restrict__ bq,
                              const float* __restrict__ bk, const float* __restrict__ v,
                              const float* __restrict__ bv, const int* __restrict__ mask,
                              float* __restrict__ scores) {
    constexpr int LDK = 264;  // 256 + 8 pad: row stride 528B -> 2-way max on b128 reads
    __shared__ unsigned short klds[64 * LDK];
    __shared__ float qp_lds[HH];
    __shared__ float v_lds[HH];
    __shared__ float red[8][64];
    int b = blockIdx.y, s0 = blockIdx.x * 64;
    int tid = threadIdx.x;

    for (int i = tid; i < HH; i += 512) {
        qp_lds[i] = qp[b * HH + i] + bq[i] + bk[i];
        v_lds[i] = v[i];
    }

    int w = tid >> 6, lane = tid & 63;
    int lq = lane >> 4, lr = lane & 15;
    int nt0 = w * 4;

    float4v acc[4][4];  // [m_tile][j]
    #pragma unroll
    for (int m = 0; m < 4; ++m)
        #pragma unroll
        for (int j = 0; j < 4; ++j) acc[m][j] = (float4v){0.f, 0.f, 0.f, 0.f};

    const short8v* Wf = (const short8v*)WkT;  // frag units: (ksg*32 + nt)*64 + lane

    for (int kc = 0; kc < 2; ++kc) {
        __syncthreads();  // protect klds reuse (no-op cost on kc=0)
        // stage 64 rows x 256 cols of keys, fp32 -> bf16 (8 float4 loads/thread)
        const float4v* ksrc = (const float4v*)(keys + ((size_t)b * SS + s0) * EE + kc * 256);
        for (int i = tid; i < 64 * 64; i += 512) {
            int row = i >> 6, c4 = i & 63;
            float4v kv = ksrc[(size_t)row * 128 + c4];
            short4v p;
            p.x = (short)f2bf(kv.x); p.y = (short)f2bf(kv.y);
            p.z = (short)f2bf(kv.z); p.w = (short)f2bf(kv.w);
            *(short4v*)(&klds[row * LDK + c4 * 4]) = p;
        }
        __syncthreads();

        #pragma unroll
        for (int ks = 0; ks < 8; ++ks) {
            int ksg = kc * 8 + ks;
            short8v bfrag[4];
            #pragma unroll
            for (int j = 0; j < 4; ++j)
                bfrag[j] = Wf[((size_t)ksg * 32 + nt0 + j) * 64 + lane];
            #pragma unroll
            for (int m = 0; m < 4; ++m) {
                short8v afrag = *(const short8v*)(&klds[(m * 16 + lr) * LDK + ks * 32 + lq * 8]);
                #pragma unroll
                for (int j = 0; j < 4; ++j)
                    acc[m][j] = __builtin_amdgcn_mfma_f32_16x16x32_bf16(afrag, bfrag[j], acc[m][j], 0, 0, 0);
            }
        }
    }

    // fused epilogue: part += v[h] * tanh(qp[h] + kp); 64 tanh per thread
    float part[4][4];
    #pragma unroll
    for (int m = 0; m < 4; ++m)
        #pragma unroll
        for (int r = 0; r < 4; ++r) part[m][r] = 0.f;
    #pragma unroll
    for (int j = 0; j < 4; ++j) {
        int h = (nt0 + j) * 16 + lr;
        float vj = v_lds[h], qj = qp_lds[h];
        #pragma unroll
        for (int m = 0; m < 4; ++m) {
            #pragma unroll
            for (int r = 0; r < 4; ++r) {
                float x = qj + acc[m][j][r];
                x = fminf(fmaxf(x, -12.f), 12.f);
                float e2 = __expf(2.f * x);
                part[m][r] += vj * ((e2 - 1.f) / (e2 + 1.f));
            }
        }
    }

    // sum across the 16 lanes of each quad-group (same s-row)
    #pragma unroll
    for (int m = 0; m < 4; ++m)
        #pragma unroll
        for (int r = 0; r < 4; ++r) {
            float p = part[m][r];
            p += __shfl_xor(p, 1, 16);
            p += __shfl_xor(p, 2, 16);
            p += __shfl_xor(p, 4, 16);
            p += __shfl_xor(p, 8, 16);
            part[m][r] = p;
        }
    if (lr == 0) {
        #pragma unroll
        for (int m = 0; m < 4; ++m)
            #pragma unroll
            for (int r = 0; r < 4; ++r)
                red[w][m * 16 + lq * 4 + r] = part[m][r];
    }
    __syncthreads();
    if (tid < 64) {
        float sc = red[0][tid] + red[1][tid] + red[2][tid] + red[3][tid]
                 + red[4][tid] + red[5][tid] + red[6][tid] + red[7][tid] + bv[0];
        int s = s0 + tid;
        if (mask[b * SS + s] == 0) sc = NEGV;
        scores[b * SS + s] = sc;
    }
}

__global__ void softmax_kernel(const float* __restrict__ scores, float* __restrict__ attn) {
    __shared__ float red[1024];
    int b = blockIdx.x, t = threadIdx.x;  // 1024 threads
    float s_[4], e_[4];
    float lmax = -3e38f;
    #pragma unroll
    for (int i = 0; i < 4; ++i) { s_[i] = scores[b * SS + t + i * 1024]; lmax = fmaxf(lmax, s_[i]); }
    red[t] = lmax; __syncthreads();
    for (int off = 512; off > 0; off >>= 1) {
        if (t < off) red[t] = fmaxf(red[t], red[t + off]);
        __syncthreads();
    }
    float mx = red[0]; __syncthreads();
    float lsum = 0.f;
    #pragma unroll
    for (int i = 0; i < 4; ++i) { e_[i] = __expf(s_[i] - mx); lsum += e_[i]; }
    red[t] = lsum; __syncthreads();
    for (int off = 512; off > 0; off >>= 1) {
        if (t < off) red[t] += red[t + off];
        __syncthreads();
    }
    float inv = 1.f / red[0];
    #pragma unroll
    for (int i = 0; i < 4; ++i) attn[b * SS + t + i * 1024] = e_[i] * inv;
}

// context[b][e] = sum_s attn[b][s]*keys[b][s][e]; grid (S/128, B).
// 4 independent FMA chains -> 4 loads in flight per iteration.
__launch_bounds__(256)
__global__ void context_kernel(const float* __restrict__ keys, const float* __restrict__ attn,
                               float* __restrict__ ctx) {
    __shared__ float a_s[128];
    int chunk = blockIdx.x, b = blockIdx.y, t = threadIdx.x;  // 256 threads
    if (t < 128) a_s[t] = attn[b * SS + chunk * 128 + t];
    __syncthreads();
    const float* kbase = keys + ((size_t)b * SS + (size_t)chunk * 128) * EE;
    int e0 = (t & 127) * 4, sr = t >> 7;
    float4v a0 = (float4v){0.f,0.f,0.f,0.f}, a1 = a0, a2 = a0, a3 = a0;
    for (int ss = sr; ss < 128; ss += 8) {
        float4v k0 = *(const float4v*)(kbase + (size_t)(ss    ) * EE + e0);
        float4v k1 = *(const float4v*)(kbase + (size_t)(ss + 2) * EE + e0);
        float4v k2 = *(const float4v*)(kbase + (size_t)(ss + 4) * EE + e0);
        float4v k3 = *(const float4v*)(kbase + (size_t)(ss + 6) * EE + e0);
        float c0 = a_s[ss], c1 = a_s[ss + 2], c2 = a_s[ss + 4], c3 = a_s[ss + 6];
        a0.x += c0*k0.x; a0.y += c0*k0.y; a0.z += c0*k0.z; a0.w += c0*k0.w;
        a1.x += c1*k1.x; a1.y += c1*k1.y; a1.z += c1*k1.z; a1.w += c1*k1.w;
        a2.x += c2*k2.x; a2.y += c2*k2.y; a2.z += c2*k2.z; a2.w += c2*k2.w;
        a3.x += c3*k3.x; a3.y += c3*k3.y; a3.z += c3*k3.z; a3.w += c3*k3.w;
    }
    float4v s4;
    s4.x = (a0.x + a1.x) + (a2.x + a3.x);
    s4.y = (a0.y + a1.y) + (a2.y + a3.y);
    s4.z = (a0.z + a1.z) + (a2.z + a3.z);
    s4.w = (a0.w + a1.w) + (a2.w + a3.w);
    atomicAdd(&ctx[b * EE + e0 + 0], s4.x);
    atomicAdd(&ctx[b * EE + e0 + 1], s4.y);
    atomicAdd(&ctx[b * EE + e0 + 2], s4.z);
    atomicAdd(&ctx[b * EE + e0 + 3], s4.w);
}

extern "C" void kernel_launch(void* const* d_in, const int* in_sizes, int n_in,
                              void* d_out, int out_size, void* d_ws, size_t ws_size,
                              hipStream_t stream) {
    const float* query = (const float*)d_in[0];
    const float* keys  = (const float*)d_in[1];
    const int*   mask  = (const int*)d_in[2];
    const float* Wq    = (const float*)d_in[3];
    const float* bq    = (const float*)d_in[4];
    const float* Wk    = (const float*)d_in[5];
    const float* bk    = (const float*)d_in[6];
    const float* v     = (const float*)d_in[7];
    const float* bv    = (const float*)d_in[8];

    float* out  = (float*)d_out;
    float* ctx  = out;            // (B, E)
    float* attn = out + BB * EE;  // (B, S)

    char* ws = (char*)d_ws;
    float* qp = (float*)ws;                                        // 65536 B
    unsigned short* WkT = (unsigned short*)(ws + 65536);           // 524288 B (fragment-linear)
    float* scores = (float*)(ws + 65536 + 524288);                 // 524288 B

    hipMemsetAsync(ctx, 0, BB * EE * sizeof(float), stream);
    hipMemsetAsync(qp, 0, BB * HH * sizeof(float), stream);
    qproj_kernel<<<dim3(4, BB), 256, 0, stream>>>(query, Wq, qp);
    wkt_kernel<<<128, 256, 0, stream>>>(Wk, WkT);
    scores_kernel<<<dim3(SS / 64, BB), 512, 0, stream>>>(keys, WkT, qp, bq, bk, v, bv, mask, scores);
    softmax_kernel<<<BB, 1024, 0, stream>>>(scores, attn);
    context_kernel<<<dim3(SS / 128, BB), 256, 0, stream>>>(keys, attn, ctx);
}

// Round 4
// 487.677 us; speedup vs baseline: 1.3182x; 1.0442x over previous
//
#include <hip/hip_runtime.h>
#include <hip/hip_bf16.h>

#define BB 32
#define SS 4096
#define HH 512
#define EE 512
#define NEGV -1000000000.0f

using float4v = __attribute__((ext_vector_type(4))) float;
using short8v = __attribute__((ext_vector_type(8))) short;
using short4v = __attribute__((ext_vector_type(4))) short;

__device__ inline unsigned short f2bf(float x) {
    union { float f; unsigned int u; } c; c.f = x;
    unsigned int r = c.u + 0x7FFFu + ((c.u >> 16) & 1u);  // RNE
    return (unsigned short)(r >> 16);
}

// Partial q-projection: grid (8, B); block handles e-range of 64, atomicAdd into qp.
__global__ void qproj_kernel(const float* __restrict__ query, const float* __restrict__ Wq,
                             float* __restrict__ qp) {
    __shared__ float qs[64];
    int b = blockIdx.y, e0 = blockIdx.x * 64, t = threadIdx.x;  // 256 threads
    if (t < 64) qs[t] = query[b * HH + e0 + t];
    __syncthreads();
    int h0 = t, h1 = t + 256;
    float a0 = 0.f, a1 = 0.f;
    #pragma unroll 8
    for (int e = 0; e < 64; ++e) {
        float q = qs[e];
        a0 += q * Wq[(size_t)(e0 + e) * HH + h0];
        a1 += q * Wq[(size_t)(e0 + e) * HH + h1];
    }
    atomicAdd(&qp[b * HH + h0], a0);
    atomicAdd(&qp[b * HH + h1], a1);
}

// Repack Wk (E,H) fp32 -> fragment-linear bf16: frag[ks][nt][lane] (16B/lane).
__global__ void wkt_kernel(const float* __restrict__ Wk, unsigned short* __restrict__ WkT) {
    int g = blockIdx.x * 256 + threadIdx.x;
    int lane = g & 63, nt = (g >> 6) & 31, ks = g >> 11;
    int lq = lane >> 4, lr = lane & 15;
    int h = nt * 16 + lr;
    int e0 = ks * 32 + lq * 8;
    short8v o;
    #pragma unroll
    for (int j = 0; j < 8; ++j) o[j] = (short)f2bf(Wk[(size_t)(e0 + j) * HH + h]);
    *(short8v*)(WkT + (size_t)g * 8) = o;
}

// Software-pipelined scores: b = blockIdx.y, 64-row s-tile, 512 threads.
// K staged in 4 chunks of 128, double-buffered LDS; next chunk's global loads
// fly under the current chunk's MFMAs (convert+store after, one barrier/chunk).
__launch_bounds__(512, 4)
__global__ void scores_kernel(const float* __restrict__ keys, const unsigned short* __restrict__ WkT,
                              const float* __restrict__ qp, const float* __restrict__ bq,
                              const float* __restrict__ bk, const float* __restrict__ v,
                              const float* __restrict__ bv, const int* __restrict__ mask,
                              float* __restrict__ scores) {
    constexpr int LDK = 136;   // 128 + 8 pad (row stride 272B == 4 banks mod 32: 2-way, free)
    constexpr int BUF = 64 * LDK;
    __shared__ unsigned short klds[2 * BUF];
    __shared__ float qp_lds[HH];
    __shared__ float v_lds[HH];
    __shared__ float red[8][64];
    int b = blockIdx.y, s0 = blockIdx.x * 64;
    int tid = threadIdx.x;

    for (int i = tid; i < HH; i += 512) {
        qp_lds[i] = qp[b * HH + i] + bq[i] + bk[i];
        v_lds[i] = v[i];
    }

    const float4v* ksrc = (const float4v*)(keys + ((size_t)b * SS + s0) * EE);
    int r0 = tid >> 5, c4 = tid & 31;   // thread stages rows r0, r0+16, r0+32, r0+48 at col-quad c4

    float4v kreg[4];
    #pragma unroll
    for (int p = 0; p < 4; ++p)
        kreg[p] = ksrc[(size_t)(p * 16 + r0) * 128 + c4];
    #pragma unroll
    for (int p = 0; p < 4; ++p) {
        short4v pk;
        pk.x = (short)f2bf(kreg[p].x); pk.y = (short)f2bf(kreg[p].y);
        pk.z = (short)f2bf(kreg[p].z); pk.w = (short)f2bf(kreg[p].w);
        *(short4v*)(&klds[(p * 16 + r0) * LDK + c4 * 4]) = pk;
    }
    __syncthreads();

    int w = tid >> 6, lane = tid & 63;
    int lq = lane >> 4, lr = lane & 15;
    int nt0 = w * 4;

    float4v acc[4][4];
    #pragma unroll
    for (int m = 0; m < 4; ++m)
        #pragma unroll
        for (int j = 0; j < 4; ++j) acc[m][j] = (float4v){0.f, 0.f, 0.f, 0.f};

    const short8v* Wf = (const short8v*)WkT;

    for (int c = 0; c < 4; ++c) {
        unsigned cur = (c & 1) * BUF;
        if (c < 3) {  // loads for chunk c+1 fly under this chunk's MFMAs
            #pragma unroll
            for (int p = 0; p < 4; ++p)
                kreg[p] = ksrc[(size_t)(p * 16 + r0) * 128 + (c + 1) * 32 + c4];
        }
        #pragma unroll
        for (int ks = 0; ks < 4; ++ks) {
            int ksg = c * 4 + ks;
            short8v bfrag[4];
            #pragma unroll
            for (int j = 0; j < 4; ++j)
                bfrag[j] = Wf[((size_t)ksg * 32 + nt0 + j) * 64 + lane];
            #pragma unroll
            for (int m = 0; m < 4; ++m) {
                short8v afrag = *(const short8v*)(&klds[cur + (m * 16 + lr) * LDK + ks * 32 + lq * 8]);
                #pragma unroll
                for (int j = 0; j < 4; ++j)
                    acc[m][j] = __builtin_amdgcn_mfma_f32_16x16x32_bf16(afrag, bfrag[j], acc[m][j], 0, 0, 0);
            }
        }
        if (c < 3) {
            unsigned nxt = ((c + 1) & 1) * BUF;
            #pragma unroll
            for (int p = 0; p < 4; ++p) {
                short4v pk;
                pk.x = (short)f2bf(kreg[p].x); pk.y = (short)f2bf(kreg[p].y);
                pk.z = (short)f2bf(kreg[p].z); pk.w = (short)f2bf(kreg[p].w);
                *(short4v*)(&klds[nxt + (p * 16 + r0) * LDK + c4 * 4]) = pk;
            }
        }
        __syncthreads();
    }

    // fused epilogue: part += v[h] * tanh(qp[h] + kp)
    float part[4][4];
    #pragma unroll
    for (int m = 0; m < 4; ++m)
        #pragma unroll
        for (int r = 0; r < 4; ++r) part[m][r] = 0.f;
    #pragma unroll
    for (int j = 0; j < 4; ++j) {
        int h = (nt0 + j) * 16 + lr;
        float vj = v_lds[h], qj = qp_lds[h];
        #pragma unroll
        for (int m = 0; m < 4; ++m) {
            #pragma unroll
            for (int r = 0; r < 4; ++r) {
                float x = qj + acc[m][j][r];
                x = fminf(fmaxf(x, -12.f), 12.f);
                float e2 = __expf(2.f * x);
                part[m][r] += vj * ((e2 - 1.f) / (e2 + 1.f));
            }
        }
    }

    #pragma unroll
    for (int m = 0; m < 4; ++m)
        #pragma unroll
        for (int r = 0; r < 4; ++r) {
            float p = part[m][r];
            p += __shfl_xor(p, 1, 16);
            p += __shfl_xor(p, 2, 16);
            p += __shfl_xor(p, 4, 16);
            p += __shfl_xor(p, 8, 16);
            part[m][r] = p;
        }
    if (lr == 0) {
        #pragma unroll
        for (int m = 0; m < 4; ++m)
            #pragma unroll
            for (int r = 0; r < 4; ++r)
                red[w][m * 16 + lq * 4 + r] = part[m][r];
    }
    __syncthreads();
    if (tid < 64) {
        float sc = red[0][tid] + red[1][tid] + red[2][tid] + red[3][tid]
                 + red[4][tid] + red[5][tid] + red[6][tid] + red[7][tid] + bv[0];
        int s = s0 + tid;
        if (mask[b * SS + s] == 0) sc = NEGV;
        scores[b * SS + s] = sc;
    }
}

__global__ void softmax_kernel(const float* __restrict__ scores, float* __restrict__ attn) {
    __shared__ float red[1024];
    int b = blockIdx.x, t = threadIdx.x;  // 1024 threads
    float s_[4], e_[4];
    float lmax = -3e38f;
    #pragma unroll
    for (int i = 0; i < 4; ++i) { s_[i] = scores[b * SS + t + i * 1024]; lmax = fmaxf(lmax, s_[i]); }
    red[t] = lmax; __syncthreads();
    for (int off = 512; off > 0; off >>= 1) {
        if (t < off) red[t] = fmaxf(red[t], red[t + off]);
        __syncthreads();
    }
    float mx = red[0]; __syncthreads();
    float lsum = 0.f;
    #pragma unroll
    for (int i = 0; i < 4; ++i) { e_[i] = __expf(s_[i] - mx); lsum += e_[i]; }
    red[t] = lsum; __syncthreads();
    for (int off = 512; off > 0; off >>= 1) {
        if (t < off) red[t] += red[t + off];
        __syncthreads();
    }
    float inv = 1.f / red[0];
    #pragma unroll
    for (int i = 0; i < 4; ++i) attn[b * SS + t + i * 1024] = e_[i] * inv;
}

// context[b][e] = sum_s attn[b][s]*keys[b][s][e]; 8-deep independent load chains.
__launch_bounds__(256)
__global__ void context_kernel(const float* __restrict__ keys, const float* __restrict__ attn,
                               float* __restrict__ ctx) {
    __shared__ float a_s[128];
    int chunk = blockIdx.x, b = blockIdx.y, t = threadIdx.x;  // 256 threads
    if (t < 128) a_s[t] = attn[b * SS + chunk * 128 + t];
    __syncthreads();
    const float* kbase = keys + ((size_t)b * SS + (size_t)chunk * 128) * EE;
    int e0 = (t & 127) * 4, sr = t >> 7;
    float4v a[8];
    #pragma unroll
    for (int u = 0; u < 8; ++u) a[u] = (float4v){0.f, 0.f, 0.f, 0.f};
    for (int ss = sr; ss < 128; ss += 16) {
        float4v k[8];
        #pragma unroll
        for (int u = 0; u < 8; ++u)
            k[u] = *(const float4v*)(kbase + (size_t)(ss + 2 * u) * EE + e0);
        #pragma unroll
        for (int u = 0; u < 8; ++u) {
            float cw = a_s[ss + 2 * u];
            a[u].x += cw * k[u].x; a[u].y += cw * k[u].y;
            a[u].z += cw * k[u].z; a[u].w += cw * k[u].w;
        }
    }
    float4v s4;
    s4.x = ((a[0].x + a[1].x) + (a[2].x + a[3].x)) + ((a[4].x + a[5].x) + (a[6].x + a[7].x));
    s4.y = ((a[0].y + a[1].y) + (a[2].y + a[3].y)) + ((a[4].y + a[5].y) + (a[6].y + a[7].y));
    s4.z = ((a[0].z + a[1].z) + (a[2].z + a[3].z)) + ((a[4].z + a[5].z) + (a[6].z + a[7].z));
    s4.w = ((a[0].w + a[1].w) + (a[2].w + a[3].w)) + ((a[4].w + a[5].w) + (a[6].w + a[7].w));
    atomicAdd(&ctx[b * EE + e0 + 0], s4.x);
    atomicAdd(&ctx[b * EE + e0 + 1], s4.y);
    atomicAdd(&ctx[b * EE + e0 + 2], s4.z);
    atomicAdd(&ctx[b * EE + e0 + 3], s4.w);
}

extern "C" void kernel_launch(void* const* d_in, const int* in_sizes, int n_in,
                              void* d_out, int out_size, void* d_ws, size_t ws_size,
                              hipStream_t stream) {
    const float* query = (const float*)d_in[0];
    const float* keys  = (const float*)d_in[1];
    const int*   mask  = (const int*)d_in[2];
    const float* Wq    = (const float*)d_in[3];
    const float* bq    = (const float*)d_in[4];
    const float* Wk    = (const float*)d_in[5];
    const float* bk    = (const float*)d_in[6];
    const float* v     = (const float*)d_in[7];
    const float* bv    = (const float*)d_in[8];

    float* out  = (float*)d_out;
    float* ctx  = out;            // (B, E)
    float* attn = out + BB * EE;  // (B, S)

    char* ws = (char*)d_ws;
    float* qp = (float*)ws;                                        // 65536 B
    unsigned short* WkT = (unsigned short*)(ws + 65536);           // 524288 B (fragment-linear)
    float* scores = (float*)(ws + 65536 + 524288);                 // 524288 B

    hipMemsetAsync(ctx, 0, BB * EE * sizeof(float), stream);
    hipMemsetAsync(qp, 0, BB * HH * sizeof(float), stream);
    qproj_kernel<<<dim3(8, BB), 256, 0, stream>>>(query, Wq, qp);
    wkt_kernel<<<128, 256, 0, stream>>>(Wk, WkT);
    scores_kernel<<<dim3(SS / 64, BB), 512, 0, stream>>>(keys, WkT, qp, bq, bk, v, bv, mask, scores);
    softmax_kernel<<<BB, 1024, 0, stream>>>(scores, attn);
    context_kernel<<<dim3(SS / 128, BB), 256, 0, stream>>>(keys, attn, ctx);
}

// Round 5
// 445.110 us; speedup vs baseline: 1.4443x; 1.0956x over previous
//
#include <hip/hip_runtime.h>
#include <hip/hip_bf16.h>

#define BB 32
#define SS 4096
#define HH 512
#define EE 512
#define NCH 64          // number of 64-row s-chunks per b
#define NEGV -1000000000.0f

using float4v = __attribute__((ext_vector_type(4))) float;
using short8v = __attribute__((ext_vector_type(8))) short;
using short4v = __attribute__((ext_vector_type(4))) short;

__device__ inline unsigned short f2bf(float x) {
    union { float f; unsigned int u; } c; c.f = x;
    unsigned int r = c.u + 0x7FFFu + ((c.u >> 16) & 1u);  // RNE
    return (unsigned short)(r >> 16);
}
__device__ inline float bf2f(unsigned short s) {
    union { float f; unsigned int u; } c; c.u = ((unsigned int)s) << 16;
    return c.f;
}

// Partial q-projection: grid (8, B); atomicAdd into qp (bq+bk folded later).
__global__ void qproj_kernel(const float* __restrict__ query, const float* __restrict__ Wq,
                             float* __restrict__ qp) {
    __shared__ float qs[64];
    int b = blockIdx.y, e0 = blockIdx.x * 64, t = threadIdx.x;  // 256 threads
    if (t < 64) qs[t] = query[b * HH + e0 + t];
    __syncthreads();
    int h0 = t, h1 = t + 256;
    float a0 = 0.f, a1 = 0.f;
    #pragma unroll 8
    for (int e = 0; e < 64; ++e) {
        float q = qs[e];
        a0 += q * Wq[(size_t)(e0 + e) * HH + h0];
        a1 += q * Wq[(size_t)(e0 + e) * HH + h1];
    }
    atomicAdd(&qp[b * HH + h0], a0);
    atomicAdd(&qp[b * HH + h1], a1);
}

// Repack Wk (E,H) fp32 -> fragment-linear bf16: frag[ks][nt][lane] (16B/lane burst).
__global__ void wkt_kernel(const float* __restrict__ Wk, unsigned short* __restrict__ WkT) {
    int g = blockIdx.x * 256 + threadIdx.x;
    int lane = g & 63, nt = (g >> 6) & 31, ks = g >> 11;
    int lq = lane >> 4, lr = lane & 15;
    int h = nt * 16 + lr;
    int e0 = ks * 32 + lq * 8;
    short8v o;
    #pragma unroll
    for (int j = 0; j < 8; ++j) o[j] = (short)f2bf(Wk[(size_t)(e0 + j) * HH + h]);
    *(short8v*)(WkT + (size_t)g * 8) = o;
}

// Fused scores + online-softmax partial + context partial.
// grid (NCH, B), 512 threads. Keys tile read ONCE from HBM, reused from LDS
// for both the k_proj MFMA (A-operand) and the weighted context sum.
__launch_bounds__(512, 4)
__global__ void fused_kernel(const float* __restrict__ keys, const unsigned short* __restrict__ WkT,
                             const float* __restrict__ qp, const float* __restrict__ bq,
                             const float* __restrict__ bk, const float* __restrict__ v,
                             const float* __restrict__ bv, const int* __restrict__ mask,
                             float* __restrict__ scores, float* __restrict__ part,
                             float* __restrict__ marr, float* __restrict__ larr) {
    constexpr int LDK = EE + 8;                 // 520 shorts, 1040B row stride
    __shared__ unsigned short klds[64 * LDK];   // 66.5 KB
    __shared__ float qp_lds[HH];
    __shared__ float v_lds[HH];
    __shared__ float red[8][64];
    __shared__ float p_lds[64];
    int b = blockIdx.y, c = blockIdx.x, s0 = c * 64;
    int tid = threadIdx.x;

    for (int i = tid; i < HH; i += 512) {
        qp_lds[i] = qp[b * HH + i] + bq[i] + bk[i];
        v_lds[i] = v[i];
    }

    // stage full 64x512 keys tile fp32 -> bf16 LDS, 4-deep load batches
    const float4v* ksrc = (const float4v*)(keys + ((size_t)b * SS + s0) * EE);
    #pragma unroll
    for (int i0 = 0; i0 < 16; i0 += 4) {
        float4v kv[4];
        #pragma unroll
        for (int p = 0; p < 4; ++p) kv[p] = ksrc[tid + (i0 + p) * 512];
        #pragma unroll
        for (int p = 0; p < 4; ++p) {
            int idx = tid + (i0 + p) * 512;
            int row = idx >> 7, c4 = idx & 127;
            short4v pk;
            pk.x = (short)f2bf(kv[p].x); pk.y = (short)f2bf(kv[p].y);
            pk.z = (short)f2bf(kv[p].z); pk.w = (short)f2bf(kv[p].w);
            *(short4v*)(&klds[row * LDK + c4 * 4]) = pk;
        }
    }
    __syncthreads();

    int w = tid >> 6, lane = tid & 63;
    int lq = lane >> 4, lr = lane & 15;
    int nt0 = w * 4;

    float4v acc[4][4];
    #pragma unroll
    for (int m = 0; m < 4; ++m)
        #pragma unroll
        for (int j = 0; j < 4; ++j) acc[m][j] = (float4v){0.f, 0.f, 0.f, 0.f};

    const short8v* Wf = (const short8v*)WkT;

    // barrier-free K-loop: B-frags stream from L2, A-frags from LDS
    #pragma unroll 2
    for (int ksg = 0; ksg < 16; ++ksg) {
        short8v bfrag[4];
        #pragma unroll
        for (int j = 0; j < 4; ++j)
            bfrag[j] = Wf[((size_t)ksg * 32 + nt0 + j) * 64 + lane];
        #pragma unroll
        for (int m = 0; m < 4; ++m) {
            short8v afrag = *(const short8v*)(&klds[(m * 16 + lr) * LDK + ksg * 32 + lq * 8]);
            #pragma unroll
            for (int j = 0; j < 4; ++j)
                acc[m][j] = __builtin_amdgcn_mfma_f32_16x16x32_bf16(afrag, bfrag[j], acc[m][j], 0, 0, 0);
        }
    }

    // fused tanh epilogue: part += v[h] * tanh(qp[h] + kp)
    float part_r[4][4];
    #pragma unroll
    for (int m = 0; m < 4; ++m)
        #pragma unroll
        for (int r = 0; r < 4; ++r) part_r[m][r] = 0.f;
    #pragma unroll
    for (int j = 0; j < 4; ++j) {
        int h = (nt0 + j) * 16 + lr;
        float vj = v_lds[h], qj = qp_lds[h];
        #pragma unroll
        for (int m = 0; m < 4; ++m) {
            #pragma unroll
            for (int r = 0; r < 4; ++r) {
                float x = qj + acc[m][j][r];
                x = fminf(fmaxf(x, -12.f), 12.f);
                float e2 = __expf(2.f * x);
                part_r[m][r] += vj * ((e2 - 1.f) / (e2 + 1.f));
            }
        }
    }
    #pragma unroll
    for (int m = 0; m < 4; ++m)
        #pragma unroll
        for (int r = 0; r < 4; ++r) {
            float p = part_r[m][r];
            p += __shfl_xor(p, 1, 16);
            p += __shfl_xor(p, 2, 16);
            p += __shfl_xor(p, 4, 16);
            p += __shfl_xor(p, 8, 16);
            part_r[m][r] = p;
        }
    if (lr == 0) {
        #pragma unroll
        for (int m = 0; m < 4; ++m)
            #pragma unroll
            for (int r = 0; r < 4; ++r)
                red[w][m * 16 + lq * 4 + r] = part_r[m][r];
    }
    __syncthreads();

    // wave 0: final score, mask, and local softmax stats over this 64-row chunk
    if (tid < 64) {
        float sc = red[0][tid] + red[1][tid] + red[2][tid] + red[3][tid]
                 + red[4][tid] + red[5][tid] + red[6][tid] + red[7][tid] + bv[0];
        int s = s0 + tid;
        if (mask[b * SS + s] == 0) sc = NEGV;
        scores[b * SS + s] = sc;
        float mv = sc;
        #pragma unroll
        for (int off = 1; off < 64; off <<= 1) mv = fmaxf(mv, __shfl_xor(mv, off));
        float pe = __expf(sc - mv);
        float ls = pe;
        #pragma unroll
        for (int off = 1; off < 64; off <<= 1) ls += __shfl_xor(ls, off);
        p_lds[tid] = pe;
        if (tid == 0) { marr[b * NCH + c] = mv; larr[b * NCH + c] = ls; }
    }
    __syncthreads();

    // context partial from the SAME LDS keys tile: o[e] = sum_s p[s]*keys[s][e]
    float o = 0.f;
    #pragma unroll 8
    for (int s = 0; s < 64; ++s)
        o += p_lds[s] * bf2f(klds[s * LDK + tid]);
    part[((size_t)b * NCH + c) * EE + tid] = o;
}

// Merge chunk partials: global max/denominator, write ctx and attn.
__global__ void finalize_kernel(const float* __restrict__ scores, const float* __restrict__ part,
                                const float* __restrict__ marr, const float* __restrict__ larr,
                                float* __restrict__ ctx, float* __restrict__ attn) {
    __shared__ float wgt[NCH];
    __shared__ float Ms, Ls;
    int b = blockIdx.x, t = threadIdx.x;  // 512 threads
    if (t < NCH) {
        float m = marr[b * NCH + t], l = larr[b * NCH + t];
        float M = m;
        #pragma unroll
        for (int off = 1; off < 64; off <<= 1) M = fmaxf(M, __shfl_xor(M, off));
        float wq = __expf(m - M);
        float L = wq * l;
        #pragma unroll
        for (int off = 1; off < 64; off <<= 1) L += __shfl_xor(L, off);
        wgt[t] = wq;
        if (t == 0) { Ms = M; Ls = L; }
    }
    __syncthreads();
    float M = Ms, invL = 1.f / Ls;
    float o = 0.f;
    #pragma unroll 8
    for (int cc = 0; cc < NCH; ++cc)
        o += wgt[cc] * part[((size_t)b * NCH + cc) * EE + t];
    ctx[b * EE + t] = o * invL;
    #pragma unroll
    for (int s = t; s < SS; s += 512)
        attn[b * SS + s] = __expf(scores[b * SS + s] - M) * invL;
}

extern "C" void kernel_launch(void* const* d_in, const int* in_sizes, int n_in,
                              void* d_out, int out_size, void* d_ws, size_t ws_size,
                              hipStream_t stream) {
    const float* query = (const float*)d_in[0];
    const float* keys  = (const float*)d_in[1];
    const int*   mask  = (const int*)d_in[2];
    const float* Wq    = (const float*)d_in[3];
    const float* bq    = (const float*)d_in[4];
    const float* Wk    = (const float*)d_in[5];
    const float* bk    = (const float*)d_in[6];
    const float* v     = (const float*)d_in[7];
    const float* bv    = (const float*)d_in[8];

    float* out  = (float*)d_out;
    float* ctx  = out;            // (B, E)
    float* attn = out + BB * EE;  // (B, S)

    char* ws = (char*)d_ws;
    float* qp           = (float*)ws;                         // 65536 B
    unsigned short* WkT = (unsigned short*)(ws + 65536);      // 524288 B
    float* scores       = (float*)(ws + 589824);              // 524288 B
    float* part         = (float*)(ws + 1114112);             // 4194304 B
    float* marr         = (float*)(ws + 5308416);             // 8192 B
    float* larr         = (float*)(ws + 5316608);             // 8192 B

    hipMemsetAsync(qp, 0, BB * HH * sizeof(float), stream);
    qproj_kernel<<<dim3(8, BB), 256, 0, stream>>>(query, Wq, qp);
    wkt_kernel<<<128, 256, 0, stream>>>(Wk, WkT);
    fused_kernel<<<dim3(NCH, BB), 512, 0, stream>>>(keys, WkT, qp, bq, bk, v, bv, mask,
                                                    scores, part, marr, larr);
    finalize_kernel<<<BB, 512, 0, stream>>>(scores, part, marr, larr, ctx, attn);
}